// Round 2
// baseline (10516.172 us; speedup 1.0000x reference)
//
#include <hip/hip_runtime.h>
#include <hip/hip_bf16.h>

typedef __bf16 bf16_t;
typedef __bf16 bf16x8 __attribute__((ext_vector_type(8)));
typedef float f32x4 __attribute__((ext_vector_type(4)));

#define NB 256      // batch
#define NTT 64      // time steps
#define NS 128      // stoch
#define ND 512      // det
#define NO 1024     // obs
#define NA 32       // act
#define NC 1152     // out channels per (b,t)
#define GSZ 128     // cooperative grid size

__device__ __forceinline__ float elu1f(float x) { return x > 0.f ? x : expm1f(x); }
__device__ __forceinline__ float sigf(float x) { return 1.f / (1.f + expf(-x)); }
__device__ __forceinline__ float sofpf(float x) { return fmaxf(x, 0.f) + log1pf(expf(-fabsf(x))); }

struct Params {
  const float* npost;                      // noise_post [B][T][128]
  const float *gb, *pb2, *pb3, *qb2;       // biases (fp32)
  float* out;                              // [B][T][1152] fp32
  unsigned* flags;                         // [GSZ] barrier flags
  bf16_t* stoch_bf;                        // [B][128]
  bf16_t* h_bf;                            // [B][512]
  float* h_f32;                            // [B][512]
  bf16_t* x1_bf;                           // [B][512]
  float* hzr;                              // [B][1024]  (h@Wh_zr + b_zr)
  float* z_f;                              // [B][512]
  bf16_t* rh_bf;                           // [B][512]   (r*h)
  float* gxa;                              // [B][512]   (gx_a + b_a)
  bf16_t* y1_bf;                           // [B][512]
  bf16_t* y2_bf;                           // [B][512]
  const bf16_t *Ww1s, *Wwi, *Wwh, *Ww2, *Ww3, *Wp1d, *Wp2;  // WT[n][k] bf16
  const bf16_t *pre_a, *pre_o;             // [T][B][512] bias included
};

// ---- custom grid barrier: per-WG flag store + wave0 polls all flags ----
__device__ __forceinline__ void gbar(unsigned* flags, unsigned gen, int wg, int tid) {
  __threadfence();   // release: flush this WG's writes to device scope
  __syncthreads();
  if (tid == 0)
    __hip_atomic_store(&flags[wg], gen, __ATOMIC_RELEASE, __HIP_MEMORY_SCOPE_AGENT);
  if (tid < 64) {
    unsigned v0, v1;
    do {
      v0 = __hip_atomic_load(&flags[tid], __ATOMIC_RELAXED, __HIP_MEMORY_SCOPE_AGENT);
      v1 = __hip_atomic_load(&flags[tid + 64], __ATOMIC_RELAXED, __HIP_MEMORY_SCOPE_AGENT);
    } while (!__all(v0 >= gen && v1 >= gen));
  }
  __syncthreads();
  __threadfence();   // acquire: invalidate stale L1 before reading others' data
}

// MF row-fragments (16 rows each) x 64 cols tile, 4 waves, MFMA 16x16x32 bf16.
// A row-major [M][lda] bf16, BT row-major [N][ldb] bf16.
template <int MF>
__device__ __forceinline__ void mmT(const bf16_t* __restrict__ A, int lda,
                                    const bf16_t* __restrict__ BT, int ldb,
                                    int K, int m0, int n0, int wave, int lane,
                                    f32x4* acc) {
  const int fr = lane & 15;
  const int kg = (lane >> 4) << 3;
  const bf16_t* a0 = A + (size_t)(m0 + fr) * lda + kg;
  const bf16_t* b0 = BT + (size_t)(n0 + (wave << 4) + fr) * ldb + kg;
  for (int k = 0; k < K; k += 32) {
    bf16x8 bfrag = *reinterpret_cast<const bf16x8*>(b0 + k);
#pragma unroll
    for (int mf = 0; mf < MF; ++mf) {
      bf16x8 afrag = *reinterpret_cast<const bf16x8*>(a0 + (size_t)(mf * 16) * lda + k);
      acc[mf] = __builtin_amdgcn_mfma_f32_16x16x32_bf16(afrag, bfrag, acc[mf], 0, 0, 0);
    }
  }
}

__global__ __launch_bounds__(256) void rssm_seq(Params p) {
  const int wg = blockIdx.x;
  const int tid = threadIdx.x;
  const int wave = tid >> 6, lane = tid & 63;
  const int fr = lane & 15, q = lane >> 4;
  unsigned gen = 0;

  for (int t = 0; t < NTT; ++t) {
    // ---- Phase A: x1 = elu(pre_a + stoch@W1s) | hzr = h@Wh[:, :1024] + b_zr
    for (int j = wg; j < 128; j += GSZ) {
      if (j < 64) {
        const int m0 = (j >> 3) << 5, n0 = (j & 7) << 6;
        f32x4 acc[2] = {};
        mmT<2>(p.stoch_bf, NS, p.Ww1s, NS, NS, m0, n0, wave, lane, acc);
        const int col = n0 + (wave << 4) + fr;
        const bf16_t* pa = p.pre_a + (size_t)t * NB * ND;
#pragma unroll
        for (int mf = 0; mf < 2; ++mf)
#pragma unroll
          for (int rr = 0; rr < 4; ++rr) {
            const int row = m0 + mf * 16 + (q << 2) + rr;
            float v = acc[mf][rr] + (float)pa[(size_t)row * ND + col];
            p.x1_bf[(size_t)row * ND + col] = (bf16_t)elu1f(v);
          }
      } else {
        const int jj = j - 64;
        const int m0 = (jj & 3) << 6, n0 = (jj >> 2) << 6;  // n0 in [0,1024)
        f32x4 acc[4] = {};
        mmT<4>(p.h_bf, ND, p.Wwh, ND, ND, m0, n0, wave, lane, acc);
        const int col = n0 + (wave << 4) + fr;
        const float bb = p.gb[col];
#pragma unroll
        for (int mf = 0; mf < 4; ++mf)
#pragma unroll
          for (int rr = 0; rr < 4; ++rr) {
            const int row = m0 + mf * 16 + (q << 2) + rr;
            p.hzr[(size_t)row * 1024 + col] = acc[mf][rr] + bb;
          }
      }
    }
    gbar(p.flags, ++gen, wg, tid);
    // ---- Phase B: per-gate jobs. gate0: z  gate1: r -> r*h  gate2: gxa
    for (int j = wg; j < 192; j += GSZ) {
      const int gate = j >> 6;
      const int jj = j & 63;
      const int m0 = (jj >> 3) << 5, n0 = (jj & 7) << 6;
      f32x4 acc[2] = {};
      mmT<2>(p.x1_bf, ND, p.Wwi + (size_t)gate * 512 * ND, ND, ND, m0, n0, wave, lane, acc);
      const int col = n0 + (wave << 4) + fr;
      if (gate == 0) {
#pragma unroll
        for (int mf = 0; mf < 2; ++mf)
#pragma unroll
          for (int rr = 0; rr < 4; ++rr) {
            const int row = m0 + mf * 16 + (q << 2) + rr;
            p.z_f[(size_t)row * ND + col] = sigf(acc[mf][rr] + p.hzr[(size_t)row * 1024 + col]);
          }
      } else if (gate == 1) {
#pragma unroll
        for (int mf = 0; mf < 2; ++mf)
#pragma unroll
          for (int rr = 0; rr < 4; ++rr) {
            const int row = m0 + mf * 16 + (q << 2) + rr;
            float rg = sigf(acc[mf][rr] + p.hzr[(size_t)row * 1024 + 512 + col]);
            p.rh_bf[(size_t)row * ND + col] = (bf16_t)(rg * p.h_f32[(size_t)row * ND + col]);
          }
      } else {
        const float bb = p.gb[1024 + col];
#pragma unroll
        for (int mf = 0; mf < 2; ++mf)
#pragma unroll
          for (int rr = 0; rr < 4; ++rr) {
            const int row = m0 + mf * 16 + (q << 2) + rr;
            p.gxa[(size_t)row * ND + col] = acc[mf][rr] + bb;
          }
      }
    }
    gbar(p.flags, ++gen, wg, tid);
    // ---- Phase C: ha = (r*h)@Wh_a ; h_new = (1-z)h + z*tanh(gxa+ha); det out
    for (int j = wg; j < 128; j += GSZ) {
      const int m0 = (j >> 3) << 4, n0 = (j & 7) << 6;
      f32x4 acc[1] = {};
      mmT<1>(p.rh_bf, ND, p.Wwh + (size_t)1024 * ND, ND, ND, m0, n0, wave, lane, acc);
      const int col = n0 + (wave << 4) + fr;
#pragma unroll
      for (int rr = 0; rr < 4; ++rr) {
        const int row = m0 + (q << 2) + rr;
        const size_t ix = (size_t)row * ND + col;
        float a = tanhf(p.gxa[ix] + acc[0][rr]);
        float zz = p.z_f[ix];
        float hn = (1.f - zz) * p.h_f32[ix] + zz * a;
        p.h_f32[ix] = hn;
        p.h_bf[ix] = (bf16_t)hn;
        p.out[((size_t)row * NTT + t) * NC + 128 + col] = hn;
      }
    }
    gbar(p.flags, ++gen, wg, tid);
    // ---- Phase D: y1 = elu(h@W2+b2) | y2 = elu(h@W1d + pre_o)
    for (int j = wg; j < 128; j += GSZ) {
      const bool isY2 = (j >= 64);
      const int jj = j & 63;
      const int m0 = (jj >> 3) << 5, n0 = (jj & 7) << 6;
      f32x4 acc[2] = {};
      mmT<2>(p.h_bf, ND, isY2 ? p.Wp1d : p.Ww2, ND, ND, m0, n0, wave, lane, acc);
      const int col = n0 + (wave << 4) + fr;
      if (!isY2) {
        const float bb = p.pb2[col];
#pragma unroll
        for (int mf = 0; mf < 2; ++mf)
#pragma unroll
          for (int rr = 0; rr < 4; ++rr) {
            const int row = m0 + mf * 16 + (q << 2) + rr;
            p.y1_bf[(size_t)row * ND + col] = (bf16_t)elu1f(acc[mf][rr] + bb);
          }
      } else {
        const bf16_t* po = p.pre_o + (size_t)t * NB * ND;
#pragma unroll
        for (int mf = 0; mf < 2; ++mf)
#pragma unroll
          for (int rr = 0; rr < 4; ++rr) {
            const int row = m0 + mf * 16 + (q << 2) + rr;
            p.y2_bf[(size_t)row * ND + col] =
                (bf16_t)elu1f(acc[mf][rr] + (float)po[(size_t)row * ND + col]);
          }
      }
    }
    gbar(p.flags, ++gen, wg, tid);
    // ---- Phase E: stats (paired mean/sigma); posterior sample fused
    for (int j = wg; j < 32; j += GSZ) {
      const bool isQ = (j >= 16);
      const int jj = j & 15;
      const int m0 = (jj >> 1) << 5, n0 = (jj & 1) << 6;
      f32x4 accM[2] = {}, accS[2] = {};
      const bf16_t* Aop = isQ ? p.y2_bf : p.y1_bf;
      const bf16_t* BT = isQ ? p.Wp2 : p.Ww3;
      {
        const int kg = q << 3;
        const bf16_t* a0 = Aop + (size_t)(m0 + fr) * ND + kg;
        const bf16_t* bm = BT + (size_t)(n0 + (wave << 4) + fr) * ND + kg;
        const bf16_t* bs = bm + (size_t)128 * ND;
        for (int k = 0; k < ND; k += 32) {
          bf16x8 bM = *reinterpret_cast<const bf16x8*>(bm + k);
          bf16x8 bS = *reinterpret_cast<const bf16x8*>(bs + k);
#pragma unroll
          for (int mf = 0; mf < 2; ++mf) {
            bf16x8 afrag = *reinterpret_cast<const bf16x8*>(a0 + (size_t)(mf * 16) * ND + k);
            accM[mf] = __builtin_amdgcn_mfma_f32_16x16x32_bf16(afrag, bM, accM[mf], 0, 0, 0);
            accS[mf] = __builtin_amdgcn_mfma_f32_16x16x32_bf16(afrag, bS, accS[mf], 0, 0, 0);
          }
        }
      }
      const int colm = n0 + (wave << 4) + fr;
      const float* bias = isQ ? p.qb2 : p.pb3;
      const float bmv = bias[colm], bsv = bias[128 + colm];
#pragma unroll
      for (int mf = 0; mf < 2; ++mf)
#pragma unroll
        for (int rr = 0; rr < 4; ++rr) {
          const int row = m0 + mf * 16 + (q << 2) + rr;
          const size_t ob = ((size_t)row * NTT + t) * NC;
          float vm = accM[mf][rr] + bmv;
          float vs = sofpf(accS[mf][rr] + bsv) + 0.1f;
          if (!isQ) {
            p.out[ob + 640 + colm] = vm;
            p.out[ob + 768 + colm] = vs;
          } else {
            float nq = p.npost[((size_t)row * NTT + t) * NS + colm];
            float st = vm + vs * nq;
            p.out[ob + colm] = st;
            p.out[ob + 896 + colm] = vm;
            p.out[ob + 1024 + colm] = vs;
            p.stoch_bf[(size_t)row * NS + colm] = (bf16_t)st;
          }
        }
    }
    gbar(p.flags, ++gen, wg, tid);
  }
}

// ---- Precompute: weight convert/transpose to bf16 WT[n][k] ----
__global__ __launch_bounds__(256) void k_wconv(
    const float* pw1, const float* gwi, const float* gwh, const float* pw2,
    const float* pw3, const float* qw1, const float* qw2,
    bf16_t* w1s, bf16_t* wi, bf16_t* wh, bf16_t* w2, bf16_t* w3,
    bf16_t* p1d, bf16_t* p2, bf16_t* wo) {
  int idx = blockIdx.x * 256 + threadIdx.x;
  if (idx < 65536) { int n = idx >> 7, k = idx & 127; w1s[idx] = (bf16_t)pw1[(32 + k) * 512 + n]; return; }
  idx -= 65536;
  if (idx < 786432) { int n = idx >> 9, k = idx & 511; wi[idx] = (bf16_t)gwi[k * 1536 + n]; return; }
  idx -= 786432;
  if (idx < 786432) { int n = idx >> 9, k = idx & 511; wh[idx] = (bf16_t)gwh[k * 1536 + n]; return; }
  idx -= 786432;
  if (idx < 262144) { int n = idx >> 9, k = idx & 511; w2[idx] = (bf16_t)pw2[k * 512 + n]; return; }
  idx -= 262144;
  if (idx < 131072) { int n = idx >> 9, k = idx & 511; w3[idx] = (bf16_t)pw3[k * 256 + n]; return; }
  idx -= 131072;
  if (idx < 262144) { int n = idx >> 9, k = idx & 511; p1d[idx] = (bf16_t)qw1[k * 512 + n]; return; }
  idx -= 262144;
  if (idx < 131072) { int n = idx >> 9, k = idx & 511; p2[idx] = (bf16_t)qw2[k * 256 + n]; return; }
  idx -= 131072;
  if (idx < 524288) { int n = idx >> 10, k = idx & 1023; wo[idx] = (bf16_t)qw1[(512 + k) * 512 + n]; return; }
}

// ---- Precompute: pre_a[t][b][n] = act[b][t]@prior_w1[:32] + prior_b1 ----
__global__ __launch_bounds__(256) void k_prea(const float* __restrict__ act,
                                              const float* __restrict__ pw1,
                                              const float* __restrict__ pb1,
                                              bf16_t* __restrict__ pre_a) {
  const int idx = blockIdx.x * 256 + threadIdx.x;  // 16384*512
  const int n = idx & 511, row = idx >> 9;
  float v = pb1[n];
  const float* ar = act + (size_t)row * NA;
#pragma unroll
  for (int k = 0; k < NA; ++k) v += ar[k] * pw1[k * 512 + n];
  const int b = row >> 6, tt = row & 63;
  pre_a[((size_t)tt * NB + b) * ND + n] = (bf16_t)v;
}

// ---- Precompute: pre_o[t][b][n] = obs[b][t]@post_w1[512:] + post_b1 (MFMA) ----
__global__ __launch_bounds__(256) void k_preo(const float* __restrict__ obs,
                                              const float* __restrict__ qb1,
                                              const bf16_t* __restrict__ wo,
                                              bf16_t* __restrict__ pre_o) {
  const int m0 = (blockIdx.x >> 3) << 6, n0 = (blockIdx.x & 7) << 6;
  const int tid = threadIdx.x, wave = tid >> 6, lane = tid & 63;
  const int fr = lane & 15, q = lane >> 4, kg = q << 3;
  f32x4 acc[4] = {};
  const float* a0 = obs + (size_t)(m0 + fr) * NO + kg;
  const bf16_t* b0 = wo + (size_t)(n0 + (wave << 4) + fr) * NO + kg;
  for (int k = 0; k < NO; k += 32) {
    bf16x8 bfrag = *reinterpret_cast<const bf16x8*>(b0 + k);
#pragma unroll
    for (int mf = 0; mf < 4; ++mf) {
      const float* ap = a0 + (size_t)(mf * 16) * NO + k;
      bf16x8 afrag;
#pragma unroll
      for (int i = 0; i < 8; ++i) afrag[i] = (bf16_t)ap[i];
      acc[mf] = __builtin_amdgcn_mfma_f32_16x16x32_bf16(afrag, bfrag, acc[mf], 0, 0, 0);
    }
  }
  const int col = n0 + (wave << 4) + fr;
  const float bb = qb1[col];
#pragma unroll
  for (int mf = 0; mf < 4; ++mf)
#pragma unroll
    for (int rr = 0; rr < 4; ++rr) {
      const int row = m0 + mf * 16 + (q << 2) + rr;
      const int b = row >> 6, tt = row & 63;
      pre_o[((size_t)tt * NB + b) * ND + col] = (bf16_t)(acc[mf][rr] + bb);
    }
}

extern "C" void kernel_launch(void* const* d_in, const int* in_sizes, int n_in,
                              void* d_out, int out_size, void* d_ws, size_t ws_size,
                              hipStream_t stream) {
  const float* obs = (const float*)d_in[0];
  const float* act = (const float*)d_in[1];
  const float* npost = (const float*)d_in[3];
  const float* pw1 = (const float*)d_in[4];
  const float* pb1 = (const float*)d_in[5];
  const float* gwi = (const float*)d_in[6];
  const float* gwh = (const float*)d_in[7];
  const float* gb = (const float*)d_in[8];
  const float* pw2 = (const float*)d_in[9];
  const float* pb2 = (const float*)d_in[10];
  const float* pw3 = (const float*)d_in[11];
  const float* pb3 = (const float*)d_in[12];
  const float* qw1 = (const float*)d_in[13];
  const float* qb1 = (const float*)d_in[14];
  const float* qw2 = (const float*)d_in[15];
  const float* qb2 = (const float*)d_in[16];

  char* ws = (char*)d_ws;
  size_t off = 0;
  auto alloc = [&](size_t bytes) {
    char* r = ws + off;
    off += (bytes + 255) & ~(size_t)255;
    return r;
  };
  // zero-init region first (state + barrier flags)
  bf16_t* stoch_bf = (bf16_t*)alloc(NB * NS * 2);
  bf16_t* h_bf = (bf16_t*)alloc(NB * ND * 2);
  float* h_f32 = (float*)alloc(NB * ND * 4);
  unsigned* flags = (unsigned*)alloc(GSZ * 4);
  const size_t zero_bytes = off;
  // per-step activations
  bf16_t* x1_bf = (bf16_t*)alloc(NB * ND * 2);
  float* hzr = (float*)alloc(NB * 1024 * 4);
  float* z_f = (float*)alloc(NB * ND * 4);
  bf16_t* rh_bf = (bf16_t*)alloc(NB * ND * 2);
  float* gxa = (float*)alloc(NB * ND * 4);
  bf16_t* y1_bf = (bf16_t*)alloc(NB * ND * 2);
  bf16_t* y2_bf = (bf16_t*)alloc(NB * ND * 2);
  // transposed weights
  bf16_t* Ww1s = (bf16_t*)alloc(512 * 128 * 2);
  bf16_t* Wwi = (bf16_t*)alloc(1536 * 512 * 2);
  bf16_t* Wwh = (bf16_t*)alloc(1536 * 512 * 2);
  bf16_t* Ww2 = (bf16_t*)alloc(512 * 512 * 2);
  bf16_t* Ww3 = (bf16_t*)alloc(256 * 512 * 2);
  bf16_t* Wp1d = (bf16_t*)alloc(512 * 512 * 2);
  bf16_t* Wp2 = (bf16_t*)alloc(256 * 512 * 2);
  bf16_t* Wo = (bf16_t*)alloc(512 * 1024 * 2);
  // precomputed streams
  bf16_t* pre_a = (bf16_t*)alloc((size_t)NTT * NB * ND * 2);
  bf16_t* pre_o = (bf16_t*)alloc((size_t)NTT * NB * ND * 2);

  hipMemsetAsync(d_ws, 0, zero_bytes, stream);

  hipLaunchKernelGGL(k_wconv, dim3(11520), dim3(256), 0, stream,
                     pw1, gwi, gwh, pw2, pw3, qw1, qw2,
                     Ww1s, Wwi, Wwh, Ww2, Ww3, Wp1d, Wp2, Wo);
  hipLaunchKernelGGL(k_prea, dim3(32768), dim3(256), 0, stream, act, pw1, pb1, pre_a);
  hipLaunchKernelGGL(k_preo, dim3(2048), dim3(256), 0, stream, obs, qb1, Wo, pre_o);

  Params p;
  p.npost = npost;
  p.gb = gb; p.pb2 = pb2; p.pb3 = pb3; p.qb2 = qb2;
  p.out = (float*)d_out;
  p.flags = flags;
  p.stoch_bf = stoch_bf; p.h_bf = h_bf; p.h_f32 = h_f32;
  p.x1_bf = x1_bf; p.hzr = hzr; p.z_f = z_f; p.rh_bf = rh_bf; p.gxa = gxa;
  p.y1_bf = y1_bf; p.y2_bf = y2_bf;
  p.Ww1s = Ww1s; p.Wwi = Wwi; p.Wwh = Wwh; p.Ww2 = Ww2; p.Ww3 = Ww3;
  p.Wp1d = Wp1d; p.Wp2 = Wp2;
  p.pre_a = pre_a; p.pre_o = pre_o;

  void* args[] = { &p };
  hipLaunchCooperativeKernel((void*)rssm_seq, dim3(GSZ), dim3(256), args, 0, stream);
}

// Round 3
// 4618.085 us; speedup vs baseline: 2.2772x; 2.2772x over previous
//
#include <hip/hip_runtime.h>
#include <hip/hip_bf16.h>

typedef __bf16 bf16_t;
typedef __bf16 bf16x8 __attribute__((ext_vector_type(8)));
typedef float f32x4 __attribute__((ext_vector_type(4)));

#define NB 256      // batch
#define NTT 64      // time steps
#define NS 128      // stoch
#define ND 512      // det
#define NO 1024     // obs
#define NA 32       // act
#define NC 1152     // out channels per (b,t)
#define GWG 32      // workgroups per XCD group
#define MROWS 32    // batch rows per group

__device__ __forceinline__ float elu1f(float x) { return x > 0.f ? x : expm1f(x); }
__device__ __forceinline__ float sigf(float x) { return 1.f / (1.f + expf(-x)); }
__device__ __forceinline__ float sofpf(float x) { return fmaxf(x, 0.f) + log1pf(expf(-fabsf(x))); }

struct Params {
  const float* npost;                      // noise_post [B][T][128]
  const float *gb, *pb2, *pb3, *qb2;       // biases (fp32)
  float* out;                              // [B][T][1152] fp32
  int* tickets;                            // [8] per-XCD ticket counters
  unsigned* flags;                         // [8*GWG] barrier flags
  bf16_t* stoch_bf;                        // [B][128]
  bf16_t* h_bf;                            // [B][512]
  float* h_f32;                            // [B][512]
  bf16_t* x1_bf;                           // [B][512]
  float* hzr;                              // [B][1024]
  float* z_f;                              // [B][512]
  bf16_t* rh_bf;                           // [B][512]
  float* gxa;                              // [B][512]
  bf16_t* y1_bf;                           // [B][512]
  bf16_t* y2_bf;                           // [B][512]
  const bf16_t *Ww1s, *Wwi, *Wwh, *Ww2, *Ww3, *Wp1d, *Wp2;  // WT[n][k] bf16
  const bf16_t *pre_a, *pre_o;             // [T][B][512] bias included
};

// XCD-local barrier among GWG workgroups pinned to one XCD.
// Data path: write-through L1 -> shared (same-XCD) L2; __syncthreads drains vmcnt.
// Flags: relaxed agent-scope atomics (no cache-maintenance emitted -> L2 stays warm).
// Consumer invalidates only its vector L1 (buffer_inv, sc1=0).
__device__ __forceinline__ void xbar(unsigned* fbase, int slot, unsigned gen, int tid) {
  __syncthreads();  // compiler emits s_waitcnt vmcnt(0) lgkmcnt(0) before s_barrier
  if (tid == 0)
    __hip_atomic_store(&fbase[slot], gen, __ATOMIC_RELAXED, __HIP_MEMORY_SCOPE_AGENT);
  if (tid < GWG) {
    while (__hip_atomic_load(&fbase[tid], __ATOMIC_RELAXED, __HIP_MEMORY_SCOPE_AGENT) < gen) {}
  }
  __syncthreads();
  asm volatile("buffer_inv" ::: "memory");  // L1-only invalidate (no sc1 -> L2 untouched)
}

// MF row-fragments (16 rows each) x 64 cols tile, 4 waves, MFMA 16x16x32 bf16.
// A row-major [M][lda] bf16, BT row-major [N][ldb] bf16.
template <int MF>
__device__ __forceinline__ void mmT(const bf16_t* __restrict__ A, int lda,
                                    const bf16_t* __restrict__ BT, int ldb,
                                    int K, int n0, int wave, int lane, f32x4* acc) {
  const int fr = lane & 15;
  const int kg = (lane >> 4) << 3;
  const bf16_t* a0 = A + (size_t)fr * lda + kg;
  const bf16_t* b0 = BT + (size_t)(n0 + (wave << 4) + fr) * ldb + kg;
  for (int k = 0; k < K; k += 32) {
    bf16x8 bfrag = *reinterpret_cast<const bf16x8*>(b0 + k);
#pragma unroll
    for (int mf = 0; mf < MF; ++mf) {
      bf16x8 afrag = *reinterpret_cast<const bf16x8*>(a0 + (size_t)(mf * 16) * lda + k);
      acc[mf] = __builtin_amdgcn_mfma_f32_16x16x32_bf16(afrag, bfrag, acc[mf], 0, 0, 0);
    }
  }
}

__global__ __launch_bounds__(256) void rssm_seq(Params p) {
  __shared__ int s_info[2];
  const int tid = threadIdx.x;
  if (tid == 0) {
    unsigned xcc;
    asm volatile("s_getreg_b32 %0, hwreg(HW_REG_XCC_ID)" : "=s"(xcc));
    xcc &= 7;
    s_info[0] = (int)xcc;
    s_info[1] = atomicAdd(&p.tickets[xcc], 1);
  }
  __syncthreads();
  const int g = s_info[0];
  const int slot = s_info[1];
  if (slot >= GWG) return;   // surplus WG on this XCD

  unsigned* fbase = p.flags + g * GWG;
  const int r0 = g * MROWS;  // this group's batch rows [r0, r0+32)
  const int wave = tid >> 6, lane = tid & 63;
  const int fr = lane & 15, q = lane >> 4;
  unsigned gen = 0;

  for (int t = 0; t < NTT; ++t) {
    // ---- Phase A: x1 = elu(pre_a + stoch@W1s) | hzr = h@Wh[:, :1024] + b_zr
    for (int j = slot; j < 24; j += GWG) {
      if (j < 8) {
        const int n0 = j << 6;
        f32x4 acc[2] = {};
        mmT<2>(p.stoch_bf + (size_t)r0 * NS, NS, p.Ww1s, NS, NS, n0, wave, lane, acc);
        const int col = n0 + (wave << 4) + fr;
        const bf16_t* pa = p.pre_a + (size_t)t * NB * ND;
#pragma unroll
        for (int mf = 0; mf < 2; ++mf)
#pragma unroll
          for (int rr = 0; rr < 4; ++rr) {
            const int row = r0 + mf * 16 + (q << 2) + rr;
            float v = acc[mf][rr] + (float)pa[(size_t)row * ND + col];
            p.x1_bf[(size_t)row * ND + col] = (bf16_t)elu1f(v);
          }
      } else {
        const int n0 = (j - 8) << 6;  // [0,1024)
        f32x4 acc[2] = {};
        mmT<2>(p.h_bf + (size_t)r0 * ND, ND, p.Wwh, ND, ND, n0, wave, lane, acc);
        const int col = n0 + (wave << 4) + fr;
        const float bb = p.gb[col];
#pragma unroll
        for (int mf = 0; mf < 2; ++mf)
#pragma unroll
          for (int rr = 0; rr < 4; ++rr) {
            const int row = r0 + mf * 16 + (q << 2) + rr;
            p.hzr[(size_t)row * 1024 + col] = acc[mf][rr] + bb;
          }
      }
    }
    xbar(fbase, slot, ++gen, tid);
    // ---- Phase B: gate0: z  gate1: r -> r*h  gate2: gxa
    for (int j = slot; j < 24; j += GWG) {
      const int gate = j >> 3;
      const int n0 = (j & 7) << 6;
      f32x4 acc[2] = {};
      mmT<2>(p.x1_bf + (size_t)r0 * ND, ND, p.Wwi + (size_t)gate * 512 * ND, ND, ND,
             n0, wave, lane, acc);
      const int col = n0 + (wave << 4) + fr;
      if (gate == 0) {
#pragma unroll
        for (int mf = 0; mf < 2; ++mf)
#pragma unroll
          for (int rr = 0; rr < 4; ++rr) {
            const int row = r0 + mf * 16 + (q << 2) + rr;
            p.z_f[(size_t)row * ND + col] = sigf(acc[mf][rr] + p.hzr[(size_t)row * 1024 + col]);
          }
      } else if (gate == 1) {
#pragma unroll
        for (int mf = 0; mf < 2; ++mf)
#pragma unroll
          for (int rr = 0; rr < 4; ++rr) {
            const int row = r0 + mf * 16 + (q << 2) + rr;
            float rg = sigf(acc[mf][rr] + p.hzr[(size_t)row * 1024 + 512 + col]);
            p.rh_bf[(size_t)row * ND + col] = (bf16_t)(rg * p.h_f32[(size_t)row * ND + col]);
          }
      } else {
        const float bb = p.gb[1024 + col];
#pragma unroll
        for (int mf = 0; mf < 2; ++mf)
#pragma unroll
          for (int rr = 0; rr < 4; ++rr) {
            const int row = r0 + mf * 16 + (q << 2) + rr;
            p.gxa[(size_t)row * ND + col] = acc[mf][rr] + bb;
          }
      }
    }
    xbar(fbase, slot, ++gen, tid);
    // ---- Phase C: ha = (r*h)@Wh_a ; h' = (1-z)h + z*tanh(gxa+ha); det out
    for (int j = slot; j < 8; j += GWG) {
      const int n0 = j << 6;
      f32x4 acc[2] = {};
      mmT<2>(p.rh_bf + (size_t)r0 * ND, ND, p.Wwh + (size_t)1024 * ND, ND, ND,
             n0, wave, lane, acc);
      const int col = n0 + (wave << 4) + fr;
#pragma unroll
      for (int mf = 0; mf < 2; ++mf)
#pragma unroll
        for (int rr = 0; rr < 4; ++rr) {
          const int row = r0 + mf * 16 + (q << 2) + rr;
          const size_t ix = (size_t)row * ND + col;
          float a = tanhf(p.gxa[ix] + acc[mf][rr]);
          float zz = p.z_f[ix];
          float hn = (1.f - zz) * p.h_f32[ix] + zz * a;
          p.h_f32[ix] = hn;
          p.h_bf[ix] = (bf16_t)hn;
          p.out[((size_t)row * NTT + t) * NC + 128 + col] = hn;
        }
    }
    xbar(fbase, slot, ++gen, tid);
    // ---- Phase D: y1 = elu(h@W2+b2) | y2 = elu(h@W1d + pre_o)
    for (int j = slot; j < 16; j += GWG) {
      const bool isY2 = (j >= 8);
      const int n0 = (j & 7) << 6;
      f32x4 acc[2] = {};
      mmT<2>(p.h_bf + (size_t)r0 * ND, ND, isY2 ? p.Wp1d : p.Ww2, ND, ND,
             n0, wave, lane, acc);
      const int col = n0 + (wave << 4) + fr;
      if (!isY2) {
        const float bb = p.pb2[col];
#pragma unroll
        for (int mf = 0; mf < 2; ++mf)
#pragma unroll
          for (int rr = 0; rr < 4; ++rr) {
            const int row = r0 + mf * 16 + (q << 2) + rr;
            p.y1_bf[(size_t)row * ND + col] = (bf16_t)elu1f(acc[mf][rr] + bb);
          }
      } else {
        const bf16_t* po = p.pre_o + (size_t)t * NB * ND;
#pragma unroll
        for (int mf = 0; mf < 2; ++mf)
#pragma unroll
          for (int rr = 0; rr < 4; ++rr) {
            const int row = r0 + mf * 16 + (q << 2) + rr;
            p.y2_bf[(size_t)row * ND + col] =
                (bf16_t)elu1f(acc[mf][rr] + (float)po[(size_t)row * ND + col]);
          }
      }
    }
    xbar(fbase, slot, ++gen, tid);
    // ---- Phase E: stats (paired mean/sigma); posterior sample fused
    for (int j = slot; j < 4; j += GWG) {
      const bool isQ = (j >= 2);
      const int n0 = (j & 1) << 6;
      f32x4 accM[2] = {}, accS[2] = {};
      const bf16_t* Aop = (isQ ? p.y2_bf : p.y1_bf) + (size_t)r0 * ND;
      const bf16_t* BT = isQ ? p.Wp2 : p.Ww3;
      {
        const int kg = q << 3;
        const bf16_t* a0 = Aop + (size_t)fr * ND + kg;
        const bf16_t* bm = BT + (size_t)(n0 + (wave << 4) + fr) * ND + kg;
        const bf16_t* bs = bm + (size_t)128 * ND;
        for (int k = 0; k < ND; k += 32) {
          bf16x8 bM = *reinterpret_cast<const bf16x8*>(bm + k);
          bf16x8 bS = *reinterpret_cast<const bf16x8*>(bs + k);
#pragma unroll
          for (int mf = 0; mf < 2; ++mf) {
            bf16x8 afrag = *reinterpret_cast<const bf16x8*>(a0 + (size_t)(mf * 16) * ND + k);
            accM[mf] = __builtin_amdgcn_mfma_f32_16x16x32_bf16(afrag, bM, accM[mf], 0, 0, 0);
            accS[mf] = __builtin_amdgcn_mfma_f32_16x16x32_bf16(afrag, bS, accS[mf], 0, 0, 0);
          }
        }
      }
      const int colm = n0 + (wave << 4) + fr;
      const float* bias = isQ ? p.qb2 : p.pb3;
      const float bmv = bias[colm], bsv = bias[128 + colm];
#pragma unroll
      for (int mf = 0; mf < 2; ++mf)
#pragma unroll
        for (int rr = 0; rr < 4; ++rr) {
          const int row = r0 + mf * 16 + (q << 2) + rr;
          const size_t ob = ((size_t)row * NTT + t) * NC;
          float vm = accM[mf][rr] + bmv;
          float vs = sofpf(accS[mf][rr] + bsv) + 0.1f;
          if (!isQ) {
            p.out[ob + 640 + colm] = vm;
            p.out[ob + 768 + colm] = vs;
          } else {
            float nq = p.npost[((size_t)row * NTT + t) * NS + colm];
            float st = vm + vs * nq;
            p.out[ob + colm] = st;
            p.out[ob + 896 + colm] = vm;
            p.out[ob + 1024 + colm] = vs;
            p.stoch_bf[(size_t)row * NS + colm] = (bf16_t)st;
          }
        }
    }
    xbar(fbase, slot, ++gen, tid);
  }
}

// ---- Precompute: weight convert/transpose to bf16 WT[n][k] ----
__global__ __launch_bounds__(256) void k_wconv(
    const float* pw1, const float* gwi, const float* gwh, const float* pw2,
    const float* pw3, const float* qw1, const float* qw2,
    bf16_t* w1s, bf16_t* wi, bf16_t* wh, bf16_t* w2, bf16_t* w3,
    bf16_t* p1d, bf16_t* p2, bf16_t* wo) {
  int idx = blockIdx.x * 256 + threadIdx.x;
  if (idx < 65536) { int n = idx >> 7, k = idx & 127; w1s[idx] = (bf16_t)pw1[(32 + k) * 512 + n]; return; }
  idx -= 65536;
  if (idx < 786432) { int n = idx >> 9, k = idx & 511; wi[idx] = (bf16_t)gwi[k * 1536 + n]; return; }
  idx -= 786432;
  if (idx < 786432) { int n = idx >> 9, k = idx & 511; wh[idx] = (bf16_t)gwh[k * 1536 + n]; return; }
  idx -= 786432;
  if (idx < 262144) { int n = idx >> 9, k = idx & 511; w2[idx] = (bf16_t)pw2[k * 512 + n]; return; }
  idx -= 262144;
  if (idx < 131072) { int n = idx >> 9, k = idx & 511; w3[idx] = (bf16_t)pw3[k * 256 + n]; return; }
  idx -= 131072;
  if (idx < 262144) { int n = idx >> 9, k = idx & 511; p1d[idx] = (bf16_t)qw1[k * 512 + n]; return; }
  idx -= 262144;
  if (idx < 131072) { int n = idx >> 9, k = idx & 511; p2[idx] = (bf16_t)qw2[k * 256 + n]; return; }
  idx -= 131072;
  if (idx < 524288) { int n = idx >> 10, k = idx & 1023; wo[idx] = (bf16_t)qw1[(512 + k) * 512 + n]; return; }
}

// ---- Precompute: pre_a[t][b][n] = act[b][t]@prior_w1[:32] + prior_b1 ----
__global__ __launch_bounds__(256) void k_prea(const float* __restrict__ act,
                                              const float* __restrict__ pw1,
                                              const float* __restrict__ pb1,
                                              bf16_t* __restrict__ pre_a) {
  const int idx = blockIdx.x * 256 + threadIdx.x;  // 16384*512
  const int n = idx & 511, row = idx >> 9;
  float v = pb1[n];
  const float* ar = act + (size_t)row * NA;
#pragma unroll
  for (int k = 0; k < NA; ++k) v += ar[k] * pw1[k * 512 + n];
  const int b = row >> 6, tt = row & 63;
  pre_a[((size_t)tt * NB + b) * ND + n] = (bf16_t)v;
}

// ---- Precompute: pre_o[t][b][n] = obs[b][t]@post_w1[512:] + post_b1 (MFMA) ----
__global__ __launch_bounds__(256) void k_preo(const float* __restrict__ obs,
                                              const float* __restrict__ qb1,
                                              const bf16_t* __restrict__ wo,
                                              bf16_t* __restrict__ pre_o) {
  const int m0 = (blockIdx.x >> 3) << 6, n0 = (blockIdx.x & 7) << 6;
  const int tid = threadIdx.x, wave = tid >> 6, lane = tid & 63;
  const int fr = lane & 15, q = lane >> 4, kg = q << 3;
  f32x4 acc[4] = {};
  const float* a0 = obs + (size_t)(m0 + fr) * NO + kg;
  const bf16_t* b0 = wo + (size_t)(n0 + (wave << 4) + fr) * NO + kg;
  for (int k = 0; k < NO; k += 32) {
    bf16x8 bfrag = *reinterpret_cast<const bf16x8*>(b0 + k);
#pragma unroll
    for (int mf = 0; mf < 4; ++mf) {
      const float* ap = a0 + (size_t)(mf * 16) * NO + k;
      bf16x8 afrag;
#pragma unroll
      for (int i = 0; i < 8; ++i) afrag[i] = (bf16_t)ap[i];
      acc[mf] = __builtin_amdgcn_mfma_f32_16x16x32_bf16(afrag, bfrag, acc[mf], 0, 0, 0);
    }
  }
  const int col = n0 + (wave << 4) + fr;
  const float bb = qb1[col];
#pragma unroll
  for (int mf = 0; mf < 4; ++mf)
#pragma unroll
    for (int rr = 0; rr < 4; ++rr) {
      const int row = m0 + mf * 16 + (q << 2) + rr;
      const int b = row >> 6, tt = row & 63;
      pre_o[((size_t)tt * NB + b) * ND + col] = (bf16_t)(acc[mf][rr] + bb);
    }
}

extern "C" void kernel_launch(void* const* d_in, const int* in_sizes, int n_in,
                              void* d_out, int out_size, void* d_ws, size_t ws_size,
                              hipStream_t stream) {
  const float* obs = (const float*)d_in[0];
  const float* act = (const float*)d_in[1];
  const float* npost = (const float*)d_in[3];
  const float* pw1 = (const float*)d_in[4];
  const float* pb1 = (const float*)d_in[5];
  const float* gwi = (const float*)d_in[6];
  const float* gwh = (const float*)d_in[7];
  const float* gb = (const float*)d_in[8];
  const float* pw2 = (const float*)d_in[9];
  const float* pb2 = (const float*)d_in[10];
  const float* pw3 = (const float*)d_in[11];
  const float* pb3 = (const float*)d_in[12];
  const float* qw1 = (const float*)d_in[13];
  const float* qb1 = (const float*)d_in[14];
  const float* qw2 = (const float*)d_in[15];
  const float* qb2 = (const float*)d_in[16];

  char* ws = (char*)d_ws;
  size_t off = 0;
  auto alloc = [&](size_t bytes) {
    char* r = ws + off;
    off += (bytes + 255) & ~(size_t)255;
    return r;
  };
  // zero-init region first (state + tickets + barrier flags)
  bf16_t* stoch_bf = (bf16_t*)alloc(NB * NS * 2);
  bf16_t* h_bf = (bf16_t*)alloc(NB * ND * 2);
  float* h_f32 = (float*)alloc(NB * ND * 4);
  int* tickets = (int*)alloc(8 * 4);
  unsigned* flags = (unsigned*)alloc(8 * GWG * 4);
  const size_t zero_bytes = off;
  // per-step activations
  bf16_t* x1_bf = (bf16_t*)alloc(NB * ND * 2);
  float* hzr = (float*)alloc(NB * 1024 * 4);
  float* z_f = (float*)alloc(NB * ND * 4);
  bf16_t* rh_bf = (bf16_t*)alloc(NB * ND * 2);
  float* gxa = (float*)alloc(NB * ND * 4);
  bf16_t* y1_bf = (bf16_t*)alloc(NB * ND * 2);
  bf16_t* y2_bf = (bf16_t*)alloc(NB * ND * 2);
  // transposed weights
  bf16_t* Ww1s = (bf16_t*)alloc(512 * 128 * 2);
  bf16_t* Wwi = (bf16_t*)alloc(1536 * 512 * 2);
  bf16_t* Wwh = (bf16_t*)alloc(1536 * 512 * 2);
  bf16_t* Ww2 = (bf16_t*)alloc(512 * 512 * 2);
  bf16_t* Ww3 = (bf16_t*)alloc(256 * 512 * 2);
  bf16_t* Wp1d = (bf16_t*)alloc(512 * 512 * 2);
  bf16_t* Wp2 = (bf16_t*)alloc(256 * 512 * 2);
  bf16_t* Wo = (bf16_t*)alloc(512 * 1024 * 2);
  // precomputed streams
  bf16_t* pre_a = (bf16_t*)alloc((size_t)NTT * NB * ND * 2);
  bf16_t* pre_o = (bf16_t*)alloc((size_t)NTT * NB * ND * 2);

  hipMemsetAsync(d_ws, 0, zero_bytes, stream);

  hipLaunchKernelGGL(k_wconv, dim3(11520), dim3(256), 0, stream,
                     pw1, gwi, gwh, pw2, pw3, qw1, qw2,
                     Ww1s, Wwi, Wwh, Ww2, Ww3, Wp1d, Wp2, Wo);
  hipLaunchKernelGGL(k_prea, dim3(32768), dim3(256), 0, stream, act, pw1, pb1, pre_a);
  hipLaunchKernelGGL(k_preo, dim3(2048), dim3(256), 0, stream, obs, qb1, Wo, pre_o);

  Params p;
  p.npost = npost;
  p.gb = gb; p.pb2 = pb2; p.pb3 = pb3; p.qb2 = qb2;
  p.out = (float*)d_out;
  p.tickets = tickets; p.flags = flags;
  p.stoch_bf = stoch_bf; p.h_bf = h_bf; p.h_f32 = h_f32;
  p.x1_bf = x1_bf; p.hzr = hzr; p.z_f = z_f; p.rh_bf = rh_bf; p.gxa = gxa;
  p.y1_bf = y1_bf; p.y2_bf = y2_bf;
  p.Ww1s = Ww1s; p.Wwi = Wwi; p.Wwh = Wwh; p.Ww2 = Ww2; p.Ww3 = Ww3;
  p.Wp1d = Wp1d; p.Wp2 = Wp2;
  p.pre_a = pre_a; p.pre_o = pre_o;

  // Over-launch; each WG self-identifies its XCD, first GWG per XCD participate.
  hipLaunchKernelGGL(rssm_seq, dim3(1024), dim3(256), 0, stream, p);
}